// Round 1
// baseline (3115.330 us; speedup 1.0000x reference)
//
#include <hip/hip_runtime.h>
#include <hip/hip_bf16.h>

// Swin window attention, B=32, H=W=56, DIM=512, HEADS=16, HD=32, WS=7, shift=3.
// Pipeline:
//  K1: qkv = roll(x) @ w_qkv, scattered to windowed layout [B][H16][win64][pos49][d32], bf16
//  K2: per (b,head,window) attention (bias + shift masks + softmax), bf16 out, same layout
//  K3: out = attn @ w_out + b_out, gathered from windowed layout, written with roll-back
// All fp32 math; bf16 only as a storage format (storage rounding ~5e-4 << 8.5e-3 threshold).

#define NWIN 64
#define NTOK 49
#define WIN_ELEMS 1568        // 49*32
#define HEAD_STRIDE 100352    // 64*49*32
#define BATCH_STRIDE 1605632  // 16*64*49*32
#define QKV_ELEMS 51380224    // 32*16*64*49*32
#define SCALE 0.17677669529663687f

struct __align__(16) bf8 { __hip_bfloat16 h[8]; };

__device__ __forceinline__ void token_decode(int t, int& b, int& i, int& j) {
  b = t / 3136;
  int r = t - b * 3136;
  i = r / 56;
  j = r - i * 56;
}

// ---------------- K1: QKV GEMM (fused roll + window scatter) ----------------
// M=100352 (rolled tokens), N=1536, K=512. 128x128 tile, BK=8, 8x8 per thread.
__global__ __launch_bounds__(256) void k_qkv(
    const float* __restrict__ x, const float* __restrict__ w,
    __hip_bfloat16* __restrict__ qb, __hip_bfloat16* __restrict__ kb,
    __hip_bfloat16* __restrict__ vb) {
  __shared__ float As[8][128];
  __shared__ float Bs[8][128];
  __shared__ const float* rowptr[128];
  const int tid = threadIdx.x;
  const int t0 = blockIdx.x * 128;
  const int n0blk = blockIdx.y * 128;

  if (tid < 128) {
    int t = t0 + tid, b, i, j;
    token_decode(t, b, i, j);
    int si = i + 3; if (si >= 56) si -= 56;   // roll(-3,-3): src = (i+3)%56
    int sj = j + 3; if (sj >= 56) sj -= 56;
    rowptr[tid] = x + ((size_t)(b * 56 + si) * 56 + sj) * 512;
  }
  __syncthreads();

  float acc[8][8] = {};
  const int arow = tid >> 1, akoff = (tid & 1) * 4;
  const int brow = tid >> 5, bcol = (tid & 31) * 4;
  const int mr = (tid >> 4) * 8, nc = (tid & 15) * 8;
  const float* wp = w + (size_t)brow * 1536 + n0blk + bcol;

  for (int kt = 0; kt < 512; kt += 8) {
    float4 a4 = *(const float4*)(rowptr[arow] + kt + akoff);
    float4 b4 = *(const float4*)(wp + (size_t)kt * 1536);
    As[akoff + 0][arow] = a4.x;
    As[akoff + 1][arow] = a4.y;
    As[akoff + 2][arow] = a4.z;
    As[akoff + 3][arow] = a4.w;
    *(float4*)&Bs[brow][bcol] = b4;
    __syncthreads();
#pragma unroll
    for (int kk = 0; kk < 8; ++kk) {
      float a0[8], b0[8];
#pragma unroll
      for (int u = 0; u < 8; ++u) a0[u] = As[kk][mr + u];
#pragma unroll
      for (int u = 0; u < 8; ++u) b0[u] = Bs[kk][nc + u];
#pragma unroll
      for (int iu = 0; iu < 8; ++iu)
#pragma unroll
        for (int ju = 0; ju < 8; ++ju)
          acc[iu][ju] = fmaf(a0[iu], b0[ju], acc[iu][ju]);
    }
    __syncthreads();
  }

  // Scatter to windowed layout. Thread's 8 columns stay within one head (8 | 32).
  const int nbase = n0blk + nc;
  const int s = nbase >> 9;            // 0=q 1=k 2=v
  const int hc = nbase & 511;
  const int h = hc >> 5, d0 = hc & 31;
  __hip_bfloat16* ob = (s == 0 ? qb : (s == 1 ? kb : vb));
  ob += (size_t)h * HEAD_STRIDE + d0;
#pragma unroll
  for (int iu = 0; iu < 8; ++iu) {
    int t = t0 + mr + iu, b, i, j;
    token_decode(t, b, i, j);
    int win = (i / 7) * 8 + (j / 7);
    int pos = (i % 7) * 7 + (j % 7);
    size_t off = (size_t)b * BATCH_STRIDE + (size_t)win * WIN_ELEMS + pos * 32;
    bf8 o;
#pragma unroll
    for (int ju = 0; ju < 8; ++ju) o.h[ju] = __float2bfloat16(acc[iu][ju]);
    *(bf8*)(ob + off) = o;
  }
}

// ---------------- K2: per-(b,head,window) attention ----------------
// grid = 32*16*64 = 32768 blocks, 256 threads.
__global__ __launch_bounds__(256) void k_attn(
    const __hip_bfloat16* __restrict__ qb, const __hip_bfloat16* __restrict__ kb,
    const __hip_bfloat16* __restrict__ vb, const float* __restrict__ pe,
    __hip_bfloat16* __restrict__ ab) {
  __shared__ float qs[49][33], ks[49][33], vs[49][33];
  __shared__ float lg[49][52];
  const int tid = threadIdx.x;
  const int gid = blockIdx.x;              // (b*16+h)*64 + win
  const int win = gid & 63;
  const int h = (gid >> 6) & 15;
  const size_t base = (size_t)gid * WIN_ELEMS;

  for (int idx = tid; idx < WIN_ELEMS; idx += 256) {
    int r = idx >> 5, d = idx & 31;
    qs[r][d] = __bfloat162float(qb[base + idx]);
    ks[r][d] = __bfloat162float(kb[base + idx]);
    vs[r][d] = __bfloat162float(vb[base + idx]);
  }
  __syncthreads();

  const bool ul = ((win >> 3) == 7);   // last window-row: upper/lower mask
  const bool lr = ((win & 7) == 7);    // last window-col: left/right mask
  for (int idx = tid; idx < 2401; idx += 256) {
    int i = idx / 49, j = idx - i * 49;
    float s = 0.f;
#pragma unroll
    for (int d = 0; d < 32; ++d) s = fmaf(qs[i][d], ks[j][d], s);
    int xi = i / 7, yi = i - xi * 7;
    int xj = j / 7, yj = j - xj * 7;
    int dx = xj - xi; if (dx < 0) dx += 13;
    int dy = yj - yi; if (dy < 0) dy += 13;
    float val = s * SCALE + pe[(dx * 13 + dy) * 16 + h];
    if ((ul && ((xi >= 4) != (xj >= 4))) || (lr && ((yi >= 4) != (yj >= 4))))
      val = -1e30f;
    lg[i][j] = val;
  }
  __syncthreads();

  // wave-parallel softmax: 4 waves, one row per wave per pass
  const int wave = tid >> 6, lane = tid & 63;
  for (int i = wave; i < 49; i += 4) {
    float xv = (lane < 49) ? lg[i][lane] : -1e30f;
    float m = xv;
#pragma unroll
    for (int off = 32; off > 0; off >>= 1) m = fmaxf(m, __shfl_xor(m, off));
    float p = __expf(xv - m);
    if (lane >= 49) p = 0.f;
    float sum = p;
#pragma unroll
    for (int off = 32; off > 0; off >>= 1) sum += __shfl_xor(sum, off);
    if (lane < 49) lg[i][lane] = p / sum;
  }
  __syncthreads();

  for (int idx = tid; idx < WIN_ELEMS; idx += 256) {
    int i = idx >> 5, d = idx & 31;
    float s = 0.f;
#pragma unroll
    for (int j = 0; j < 49; ++j) s = fmaf(lg[i][j], vs[j][d], s);
    ab[base + idx] = __float2bfloat16(s);
  }
}

// ---------------- K3: output GEMM (window gather + roll-back scatter) ----------------
// M=100352, N=512, K=512. 128x128 tile, BK=16, 8x8 per thread.
__global__ __launch_bounds__(256) void k_out(
    const __hip_bfloat16* __restrict__ ab, const float* __restrict__ w,
    const float* __restrict__ bias, float* __restrict__ out) {
  __shared__ float As[16][128];
  __shared__ float Bs[16][128];
  __shared__ size_t rowoff[128];
  const int tid = threadIdx.x;
  const int t0 = blockIdx.x * 128;
  const int n0blk = blockIdx.y * 128;

  if (tid < 128) {
    int t = t0 + tid, b, i, j;
    token_decode(t, b, i, j);
    int win = (i / 7) * 8 + (j / 7);
    int pos = (i % 7) * 7 + (j % 7);
    rowoff[tid] = (size_t)b * BATCH_STRIDE + (size_t)win * WIN_ELEMS + pos * 32;
  }
  __syncthreads();

  float acc[8][8] = {};
  const int arow = tid >> 1, koff = (tid & 1) * 8;
  const int brow = tid >> 4, bcol = (tid & 15) * 8;
  const int mr = (tid >> 4) * 8, nc = (tid & 15) * 8;

  for (int kt = 0; kt < 512; kt += 16) {
    int k0 = kt + koff;
    int h = k0 >> 5, d0 = k0 & 31;             // 8 consecutive d stay in one head
    bf8 a8 = *(const bf8*)(ab + rowoff[arow] + (size_t)h * HEAD_STRIDE + d0);
    const float* bp = w + (size_t)(kt + brow) * 512 + n0blk + bcol;
    float4 b40 = *(const float4*)bp;
    float4 b41 = *(const float4*)(bp + 4);
#pragma unroll
    for (int u = 0; u < 8; ++u) As[koff + u][arow] = __bfloat162float(a8.h[u]);
    *(float4*)&Bs[brow][bcol] = b40;
    *(float4*)&Bs[brow][bcol + 4] = b41;
    __syncthreads();
#pragma unroll
    for (int kk = 0; kk < 16; ++kk) {
      float a0[8], b0[8];
#pragma unroll
      for (int u = 0; u < 8; ++u) a0[u] = As[kk][mr + u];
#pragma unroll
      for (int u = 0; u < 8; ++u) b0[u] = Bs[kk][nc + u];
#pragma unroll
      for (int iu = 0; iu < 8; ++iu)
#pragma unroll
        for (int ju = 0; ju < 8; ++ju)
          acc[iu][ju] = fmaf(a0[iu], b0[ju], acc[iu][ju]);
    }
    __syncthreads();
  }

  const int n0 = n0blk + nc;
  float4 bv0 = *(const float4*)(bias + n0);
  float4 bv1 = *(const float4*)(bias + n0 + 4);
#pragma unroll
  for (int iu = 0; iu < 8; ++iu) {
    int t = t0 + mr + iu, b, i, j;
    token_decode(t, b, i, j);
    int di = i + 3; if (di >= 56) di -= 56;    // roll(+3,+3) on write
    int dj = j + 3; if (dj >= 56) dj -= 56;
    float* op = out + ((size_t)(b * 56 + di) * 56 + dj) * 512 + n0;
    float4 o0 = make_float4(acc[iu][0] + bv0.x, acc[iu][1] + bv0.y,
                            acc[iu][2] + bv0.z, acc[iu][3] + bv0.w);
    float4 o1 = make_float4(acc[iu][4] + bv1.x, acc[iu][5] + bv1.y,
                            acc[iu][6] + bv1.z, acc[iu][7] + bv1.w);
    *(float4*)op = o0;
    *(float4*)(op + 4) = o1;
  }
}

extern "C" void kernel_launch(void* const* d_in, const int* in_sizes, int n_in,
                              void* d_out, int out_size, void* d_ws, size_t ws_size,
                              hipStream_t stream) {
  const float* x     = (const float*)d_in[0];
  const float* w_qkv = (const float*)d_in[1];
  const float* pe    = (const float*)d_in[2];
  const float* w_out = (const float*)d_in[3];
  const float* b_out = (const float*)d_in[4];
  float* out = (float*)d_out;

  __hip_bfloat16* qb = (__hip_bfloat16*)d_ws;           // 4 x 102.8 MB bf16 in scratch
  __hip_bfloat16* kb = qb + (size_t)QKV_ELEMS;
  __hip_bfloat16* vb = kb + (size_t)QKV_ELEMS;
  __hip_bfloat16* ab = vb + (size_t)QKV_ELEMS;

  k_qkv<<<dim3(784, 12), dim3(256), 0, stream>>>(x, w_qkv, qb, kb, vb);
  k_attn<<<dim3(32768), dim3(256), 0, stream>>>(qb, kb, vb, pe, ab);
  k_out<<<dim3(784, 4), dim3(256), 0, stream>>>(ab, w_out, b_out, out);
}

// Round 2
// 1079.669 us; speedup vs baseline: 2.8854x; 2.8854x over previous
//
#include <hip/hip_runtime.h>
#include <hip/hip_bf16.h>
#include <stdint.h>

// Swin window attention, B=32, H=W=56, DIM=512, HEADS=16, HD=32, WS=7, shift=3.
// Round 2: both GEMMs converted to bf16 MFMA (16x16x32), m97-style 128x128 tile,
// BK=64, global_load_lds width-16 staging, fp32 accumulate.
//  P1: xb = bf16(roll(x))            [token][512]
//  P2: wbt = bf16(w_qkv^T)           [1536][512]
//  P3: wot = bf16(w_out^T)           [512][512]
//  K1: qkv windowed bf16 [B][H16][win64][pos49][d32]  (MFMA)
//  K2: per-window attention, fp32 math                (unchanged)
//  K3: out = attn @ w_out + bias, roll-back           (MFMA)

#define NWIN 64
#define NTOK 49
#define WIN_ELEMS 1568        // 49*32
#define HEAD_STRIDE 100352    // 64*49*32
#define BATCH_STRIDE 1605632  // 16*64*49*32
#define QKV_ELEMS 51380224    // 32*16*64*49*32
#define SCALE 0.17677669529663687f

typedef __attribute__((ext_vector_type(8))) short bf16x8;
typedef __attribute__((ext_vector_type(4))) float f32x4;

#define AS1 __attribute__((address_space(1)))
#define AS3 __attribute__((address_space(3)))

struct __align__(16) bf8 { __hip_bfloat16 h[8]; };

__device__ __forceinline__ void gload_lds16(const void* g, void* l) {
  __builtin_amdgcn_global_load_lds((const AS1 unsigned int*)g,
                                   (AS3 unsigned int*)l, 16, 0, 0);
}

__device__ __forceinline__ void token_decode(int t, int& b, int& i, int& j) {
  b = t / 3136;
  int r = t - b * 3136;
  i = r / 56;
  j = r - i * 56;
}

// ---------------- P1: x -> bf16, roll(-3,-3) fused, token-major ----------------
__global__ __launch_bounds__(256) void k_prep_x(const float* __restrict__ x,
                                                __hip_bfloat16* __restrict__ xb) {
  int idx = blockIdx.x * 256 + threadIdx.x;    // one per 8 elements
  int t = idx >> 6;
  int c = (idx & 63) * 8;
  int b, i, j;
  token_decode(t, b, i, j);
  int si = i + 3; if (si >= 56) si -= 56;
  int sj = j + 3; if (sj >= 56) sj -= 56;
  const float* src = x + ((size_t)(b * 56 + si) * 56 + sj) * 512 + c;
  float4 a0 = *(const float4*)src;
  float4 a1 = *(const float4*)(src + 4);
  bf8 o;
  o.h[0] = __float2bfloat16(a0.x); o.h[1] = __float2bfloat16(a0.y);
  o.h[2] = __float2bfloat16(a0.z); o.h[3] = __float2bfloat16(a0.w);
  o.h[4] = __float2bfloat16(a1.x); o.h[5] = __float2bfloat16(a1.y);
  o.h[6] = __float2bfloat16(a1.z); o.h[7] = __float2bfloat16(a1.w);
  *(bf8*)(xb + (size_t)t * 512 + c) = o;
}

// ---------------- P2/P3: fp32 [K][N] -> bf16 [N][K] transpose ----------------
__global__ __launch_bounds__(256) void k_transpose(const float* __restrict__ in,
                                                   __hip_bfloat16* __restrict__ out,
                                                   int K, int N) {
  __shared__ float tl[64][65];
  const int nb = blockIdx.x * 64, kb = blockIdx.y * 64;
  const int tid = threadIdx.x;
#pragma unroll
  for (int s = 0; s < 16; ++s) {
    int idx = s * 256 + tid; int r = idx >> 6, c = idx & 63;
    tl[r][c] = in[(size_t)(kb + r) * N + nb + c];
  }
  __syncthreads();
#pragma unroll
  for (int s = 0; s < 16; ++s) {
    int idx = s * 256 + tid; int r = idx >> 6, c = idx & 63;
    out[(size_t)(nb + r) * K + kb + c] = __float2bfloat16(tl[c][r]);
  }
}

// ---------------- K1: QKV GEMM, bf16 MFMA ----------------
// M=100352, N=1536, K=512. 128x128 tile, BK=64, 4 waves (2x2), 64x64 per wave.
__global__ __launch_bounds__(256) void k_qkv_mfma(
    const __hip_bfloat16* __restrict__ xb, const __hip_bfloat16* __restrict__ wbt,
    __hip_bfloat16* __restrict__ qb, __hip_bfloat16* __restrict__ kb,
    __hip_bfloat16* __restrict__ vb) {
  __shared__ __align__(16) short As[128 * 64];
  __shared__ __align__(16) short Bs[128 * 64];
  const int tid = threadIdx.x;
  const int t0 = blockIdx.x * 128;
  const int n0 = blockIdx.y * 128;
  const int lane = tid & 63, wave = tid >> 6;
  const int wm = wave >> 1, wn = wave & 1;

  // staging sources: chunk c = s*256+tid -> tile row c>>3, k-chunk (c&7)*8
  const __hip_bfloat16* asrc[4];
  const __hip_bfloat16* bsrc[4];
#pragma unroll
  for (int s = 0; s < 4; ++s) {
    int c = s * 256 + tid;
    int row = c >> 3, kc = c & 7;
    asrc[s] = xb + (size_t)(t0 + row) * 512 + kc * 8;
    bsrc[s] = wbt + (size_t)(n0 + row) * 512 + kc * 8;
  }
  char* abase = (char*)As + wave * 1024;
  char* bbase = (char*)Bs + wave * 1024;

  f32x4 acc[4][4] = {};
  const int arow = wm * 64 + (lane & 15);
  const int brow = wn * 64 + (lane & 15);
  const int koff = (lane >> 4) * 8;

  for (int kt = 0; kt < 512; kt += 64) {
#pragma unroll
    for (int s = 0; s < 4; ++s) gload_lds16(asrc[s] + kt, abase + s * 4096);
#pragma unroll
    for (int s = 0; s < 4; ++s) gload_lds16(bsrc[s] + kt, bbase + s * 4096);
    __syncthreads();
    bf16x8 af[2][4], bfr[2][4];
#pragma unroll
    for (int kk = 0; kk < 2; ++kk) {
#pragma unroll
      for (int mf = 0; mf < 4; ++mf)
        af[kk][mf] = *(const bf16x8*)&As[(arow + mf * 16) * 64 + kk * 32 + koff];
#pragma unroll
      for (int nf = 0; nf < 4; ++nf)
        bfr[kk][nf] = *(const bf16x8*)&Bs[(brow + nf * 16) * 64 + kk * 32 + koff];
    }
#pragma unroll
    for (int kk = 0; kk < 2; ++kk)
#pragma unroll
      for (int mf = 0; mf < 4; ++mf)
#pragma unroll
        for (int nf = 0; nf < 4; ++nf)
          acc[mf][nf] = __builtin_amdgcn_mfma_f32_16x16x32_bf16(
              af[kk][mf], bfr[kk][nf], acc[mf][nf], 0, 0, 0);
    __syncthreads();
  }

  // epilogue: scatter to windowed layout [b][h][win][pos][d], bf16
  __hip_bfloat16* obs[4];
#pragma unroll
  for (int nf = 0; nf < 4; ++nf) {
    int n = n0 + wn * 64 + nf * 16 + (lane & 15);
    int sp = n >> 9, hc = n & 511, h = hc >> 5, d = hc & 31;
    obs[nf] = (sp == 0 ? qb : (sp == 1 ? kb : vb)) + (size_t)h * HEAD_STRIDE + d;
  }
#pragma unroll
  for (int mf = 0; mf < 4; ++mf) {
#pragma unroll
    for (int r = 0; r < 4; ++r) {
      int t = t0 + wm * 64 + mf * 16 + (lane >> 4) * 4 + r;
      int b, i, j;
      token_decode(t, b, i, j);
      int win = (i / 7) * 8 + (j / 7);
      int pos = (i % 7) * 7 + (j % 7);
      size_t off = (size_t)b * BATCH_STRIDE + (size_t)win * WIN_ELEMS + pos * 32;
#pragma unroll
      for (int nf = 0; nf < 4; ++nf)
        obs[nf][off] = __float2bfloat16(acc[mf][nf][r]);
    }
  }
}

// ---------------- K2: per-(b,head,window) attention (fp32 math) ----------------
__global__ __launch_bounds__(256) void k_attn(
    const __hip_bfloat16* __restrict__ qb, const __hip_bfloat16* __restrict__ kb,
    const __hip_bfloat16* __restrict__ vb, const float* __restrict__ pe,
    __hip_bfloat16* __restrict__ ab) {
  __shared__ float qs[49][33], ks[49][33], vs[49][33];
  __shared__ float lg[49][52];
  const int tid = threadIdx.x;
  const int gid = blockIdx.x;
  const int win = gid & 63;
  const int h = (gid >> 6) & 15;
  const size_t base = (size_t)gid * WIN_ELEMS;

  if (tid < 196) {                         // vectorized loads: 196 chunks of 8
    int r = tid >> 2, d0 = (tid & 3) * 8;
    bf8 q8 = *(const bf8*)(qb + base + tid * 8);
    bf8 k8 = *(const bf8*)(kb + base + tid * 8);
    bf8 v8 = *(const bf8*)(vb + base + tid * 8);
#pragma unroll
    for (int u = 0; u < 8; ++u) {
      qs[r][d0 + u] = __bfloat162float(q8.h[u]);
      ks[r][d0 + u] = __bfloat162float(k8.h[u]);
      vs[r][d0 + u] = __bfloat162float(v8.h[u]);
    }
  }
  __syncthreads();

  const bool ul = ((win >> 3) == 7);
  const bool lr = ((win & 7) == 7);
  for (int idx = tid; idx < 2401; idx += 256) {
    int i = idx / 49, j = idx - i * 49;
    float s = 0.f;
#pragma unroll
    for (int d = 0; d < 32; ++d) s = fmaf(qs[i][d], ks[j][d], s);
    int xi = i / 7, yi = i - xi * 7;
    int xj = j / 7, yj = j - xj * 7;
    int dx = xj - xi; if (dx < 0) dx += 13;
    int dy = yj - yi; if (dy < 0) dy += 13;
    float val = s * SCALE + pe[(dx * 13 + dy) * 16 + h];
    if ((ul && ((xi >= 4) != (xj >= 4))) || (lr && ((yi >= 4) != (yj >= 4))))
      val = -1e30f;
    lg[i][j] = val;
  }
  __syncthreads();

  const int wave = tid >> 6, lane = tid & 63;
  for (int i = wave; i < 49; i += 4) {
    float xv = (lane < 49) ? lg[i][lane] : -1e30f;
    float m = xv;
#pragma unroll
    for (int off = 32; off > 0; off >>= 1) m = fmaxf(m, __shfl_xor(m, off));
    float p = __expf(xv - m);
    if (lane >= 49) p = 0.f;
    float sum = p;
#pragma unroll
    for (int off = 32; off > 0; off >>= 1) sum += __shfl_xor(sum, off);
    if (lane < 49) lg[i][lane] = p / sum;
  }
  __syncthreads();

  for (int idx = tid; idx < WIN_ELEMS; idx += 256) {
    int i = idx >> 5, d = idx & 31;
    float s = 0.f;
#pragma unroll
    for (int j = 0; j < 49; ++j) s = fmaf(lg[i][j], vs[j][d], s);
    ab[base + idx] = __float2bfloat16(s);
  }
}

// ---------------- K3: output GEMM, bf16 MFMA ----------------
// M=100352, N=512, K=512. A gathered from windowed ab layout.
__global__ __launch_bounds__(256) void k_out_mfma(
    const __hip_bfloat16* __restrict__ ab, const __hip_bfloat16* __restrict__ wot,
    const float* __restrict__ bias, float* __restrict__ out) {
  __shared__ __align__(16) short As[128 * 64];
  __shared__ __align__(16) short Bs[128 * 64];
  const int tid = threadIdx.x;
  const int t0 = blockIdx.x * 128;
  const int n0 = blockIdx.y * 128;
  const int lane = tid & 63, wave = tid >> 6;
  const int wm = wave >> 1, wn = wave & 1;

  size_t aoff[4];
  const __hip_bfloat16* bsrc[4];
#pragma unroll
  for (int s = 0; s < 4; ++s) {
    int c = s * 256 + tid;
    int row = c >> 3, kc = c & 7;
    int t = t0 + row, b, i, j;
    token_decode(t, b, i, j);
    int win = (i / 7) * 8 + (j / 7);
    int pos = (i % 7) * 7 + (j % 7);
    aoff[s] = (size_t)b * BATCH_STRIDE + (size_t)win * WIN_ELEMS + pos * 32 +
              (size_t)(kc >> 2) * HEAD_STRIDE + (kc & 3) * 8;
    bsrc[s] = wot + (size_t)(n0 + row) * 512 + kc * 8;
  }
  char* abase = (char*)As + wave * 1024;
  char* bbase = (char*)Bs + wave * 1024;

  f32x4 acc[4][4] = {};
  const int arow = wm * 64 + (lane & 15);
  const int brow = wn * 64 + (lane & 15);
  const int koff = (lane >> 4) * 8;

  for (int kt = 0; kt < 512; kt += 64) {
    size_t hoff = (size_t)(kt >> 5) * HEAD_STRIDE;
#pragma unroll
    for (int s = 0; s < 4; ++s) gload_lds16(ab + aoff[s] + hoff, abase + s * 4096);
#pragma unroll
    for (int s = 0; s < 4; ++s) gload_lds16(bsrc[s] + kt, bbase + s * 4096);
    __syncthreads();
    bf16x8 af[2][4], bfr[2][4];
#pragma unroll
    for (int kk = 0; kk < 2; ++kk) {
#pragma unroll
      for (int mf = 0; mf < 4; ++mf)
        af[kk][mf] = *(const bf16x8*)&As[(arow + mf * 16) * 64 + kk * 32 + koff];
#pragma unroll
      for (int nf = 0; nf < 4; ++nf)
        bfr[kk][nf] = *(const bf16x8*)&Bs[(brow + nf * 16) * 64 + kk * 32 + koff];
    }
#pragma unroll
    for (int kk = 0; kk < 2; ++kk)
#pragma unroll
      for (int mf = 0; mf < 4; ++mf)
#pragma unroll
        for (int nf = 0; nf < 4; ++nf)
          acc[mf][nf] = __builtin_amdgcn_mfma_f32_16x16x32_bf16(
              af[kk][mf], bfr[kk][nf], acc[mf][nf], 0, 0, 0);
    __syncthreads();
  }

  float bia[4];
#pragma unroll
  for (int nf = 0; nf < 4; ++nf)
    bia[nf] = bias[n0 + wn * 64 + nf * 16 + (lane & 15)];

#pragma unroll
  for (int mf = 0; mf < 4; ++mf) {
#pragma unroll
    for (int r = 0; r < 4; ++r) {
      int t = t0 + wm * 64 + mf * 16 + (lane >> 4) * 4 + r;
      int b, i, j;
      token_decode(t, b, i, j);
      int di = i + 3; if (di >= 56) di -= 56;   // roll(+3,+3) on write
      int dj = j + 3; if (dj >= 56) dj -= 56;
      float* op = out + ((size_t)(b * 56 + di) * 56 + dj) * 512 + n0 + wn * 64 +
                  (lane & 15);
#pragma unroll
      for (int nf = 0; nf < 4; ++nf) op[nf * 16] = acc[mf][nf][r] + bia[nf];
    }
  }
}

extern "C" void kernel_launch(void* const* d_in, const int* in_sizes, int n_in,
                              void* d_out, int out_size, void* d_ws, size_t ws_size,
                              hipStream_t stream) {
  const float* x     = (const float*)d_in[0];
  const float* w_qkv = (const float*)d_in[1];
  const float* pe    = (const float*)d_in[2];
  const float* w_out = (const float*)d_in[3];
  const float* b_out = (const float*)d_in[4];
  float* out = (float*)d_out;

  __hip_bfloat16* qb  = (__hip_bfloat16*)d_ws;
  __hip_bfloat16* kb  = qb + (size_t)QKV_ELEMS;
  __hip_bfloat16* vb  = kb + (size_t)QKV_ELEMS;
  __hip_bfloat16* xb  = vb + (size_t)QKV_ELEMS;     // aliased: xb (pre-attn) / ab (post-attn)
  __hip_bfloat16* ab  = xb;
  __hip_bfloat16* wbt = xb + (size_t)QKV_ELEMS;     // 1536*512 bf16
  __hip_bfloat16* wot = wbt + (size_t)(1536 * 512); // 512*512 bf16

  k_prep_x<<<dim3(25088), dim3(256), 0, stream>>>(x, xb);
  k_transpose<<<dim3(24, 8), dim3(256), 0, stream>>>(w_qkv, wbt, 512, 1536);
  k_transpose<<<dim3(8, 8), dim3(256), 0, stream>>>(w_out, wot, 512, 512);
  k_qkv_mfma<<<dim3(784, 12), dim3(256), 0, stream>>>(xb, wbt, qb, kb, vb);
  k_attn<<<dim3(32768), dim3(256), 0, stream>>>(qb, kb, vb, pe, ab);
  k_out_mfma<<<dim3(784, 4), dim3(256), 0, stream>>>(ab, wot, b_out, out);
}

// Round 3
// 692.416 us; speedup vs baseline: 4.4992x; 1.5593x over previous
//
#include <hip/hip_runtime.h>
#include <hip/hip_bf16.h>
#include <stdint.h>

// Swin window attention, B=32, H=W=56, DIM=512, HEADS=16, HD=32, WS=7, shift=3.
// Round 3: attention converted to MFMA. One wave per (b,head,win); S^T = mfma(K,Q)
// so softmax key-reduce is 2 shuffles; bias+masks pre-baked into fragment-layout
// table; V stored transposed [d32][tok56] so PV B-frags are contiguous.

#define NWIN 64
#define NTOK 49
#define WIN_ELEMS 1568        // 49*32
#define HEAD_STRIDE 100352    // 64*49*32
#define BATCH_STRIDE 1605632  // 16*64*49*32
#define QKV_ELEMS 51380224    // 32*16*64*49*32
#define VT_WIN 1792           // 32*56
#define VT_HEAD 114688        // 64*1792
#define VT_BATCH 1835008      // 16*114688
#define VT_ELEMS 58720256     // 32*1835008
#define SCALE 0.17677669529663687f

typedef __attribute__((ext_vector_type(8))) short bf16x8;
typedef __attribute__((ext_vector_type(4))) float f32x4;

#define AS1 __attribute__((address_space(1)))
#define AS3 __attribute__((address_space(3)))

struct __align__(16) bf8 { __hip_bfloat16 h[8]; };

__device__ __forceinline__ void gload_lds16(const void* g, void* l) {
  __builtin_amdgcn_global_load_lds((const AS1 unsigned int*)g,
                                   (AS3 unsigned int*)l, 16, 0, 0);
}

__device__ __forceinline__ void token_decode(int t, int& b, int& i, int& j) {
  b = t / 3136;
  int r = t - b * 3136;
  i = r / 56;
  j = r - i * 56;
}

// ---------------- P0: zero V-transpose tok padding (before k_qkv) ----------------
__global__ __launch_bounds__(256) void k_zero_vpad(__hip_bfloat16* __restrict__ vt) {
  size_t r = (size_t)blockIdx.x * 256 + threadIdx.x;   // 1,048,576 rows of 56
  float4 z = make_float4(0.f, 0.f, 0.f, 0.f);
  *(float4*)((char*)vt + r * 112 + 96) = z;            // zero toks 48..55 (48 rewritten)
}

// ---------------- P1: x -> bf16, roll(-3,-3) fused, token-major ----------------
__global__ __launch_bounds__(256) void k_prep_x(const float* __restrict__ x,
                                                __hip_bfloat16* __restrict__ xb) {
  int idx = blockIdx.x * 256 + threadIdx.x;
  int t = idx >> 6;
  int c = (idx & 63) * 8;
  int b, i, j;
  token_decode(t, b, i, j);
  int si = i + 3; if (si >= 56) si -= 56;
  int sj = j + 3; if (sj >= 56) sj -= 56;
  const float* src = x + ((size_t)(b * 56 + si) * 56 + sj) * 512 + c;
  float4 a0 = *(const float4*)src;
  float4 a1 = *(const float4*)(src + 4);
  bf8 o;
  o.h[0] = __float2bfloat16(a0.x); o.h[1] = __float2bfloat16(a0.y);
  o.h[2] = __float2bfloat16(a0.z); o.h[3] = __float2bfloat16(a0.w);
  o.h[4] = __float2bfloat16(a1.x); o.h[5] = __float2bfloat16(a1.y);
  o.h[6] = __float2bfloat16(a1.z); o.h[7] = __float2bfloat16(a1.w);
  *(bf8*)(xb + (size_t)t * 512 + c) = o;
}

// ---------------- P2/P3: fp32 [K][N] -> bf16 [N][K] transpose ----------------
__global__ __launch_bounds__(256) void k_transpose(const float* __restrict__ in,
                                                   __hip_bfloat16* __restrict__ out,
                                                   int K, int N) {
  __shared__ float tl[64][65];
  const int nb = blockIdx.x * 64, kb = blockIdx.y * 64;
  const int tid = threadIdx.x;
#pragma unroll
  for (int s = 0; s < 16; ++s) {
    int idx = s * 256 + tid; int r = idx >> 6, c = idx & 63;
    tl[r][c] = in[(size_t)(kb + r) * N + nb + c];
  }
  __syncthreads();
#pragma unroll
  for (int s = 0; s < 16; ++s) {
    int idx = s * 256 + tid; int r = idx >> 6, c = idx & 63;
    out[(size_t)(nb + r) * K + kb + c] = __float2bfloat16(tl[c][r]);
  }
}

// ---------------- P4: bias table in MFMA fragment layout ----------------
// biasT[wtype][h][mf][r][lane][nf] f32: value at S^T[key][query], -1e30 for
// masked / padded entries. key = mf*16+(lane>>4)*4+r, query = nf*16+(lane&15).
__global__ __launch_bounds__(256) void k_prep_bias(const float* __restrict__ pe,
                                                   float* __restrict__ biasT) {
  int id = blockIdx.x * 256 + threadIdx.x;      // 262144 total
  int whid = id >> 12;
  int wtype = whid >> 4, h = whid & 15;
  int mid = id & 4095;
  int mf = mid >> 10, r = (mid >> 8) & 3, lane = (mid >> 2) & 63, nf = mid & 3;
  int key = mf * 16 + (lane >> 4) * 4 + r;
  int query = nf * 16 + (lane & 15);
  float v;
  if (key >= 49 || query >= 49) {
    v = -1e30f;
  } else {
    int i = query, j = key;
    int xi = i / 7, yi = i - xi * 7;
    int xj = j / 7, yj = j - xj * 7;
    int dx = xj - xi; if (dx < 0) dx += 13;
    int dy = yj - yi; if (dy < 0) dy += 13;
    v = pe[(dx * 13 + dy) * 16 + h];
    if ((wtype & 1) && ((xi >= 4) != (xj >= 4))) v = -1e30f;
    if ((wtype & 2) && ((yi >= 4) != (yj >= 4))) v = -1e30f;
  }
  biasT[id] = v;
}

// ---------------- K1: QKV GEMM, bf16 MFMA ----------------
// M=100352, N=1536, K=512. 128x128 tile, BK=64, 4 waves (2x2), 64x64 per wave.
__global__ __launch_bounds__(256) void k_qkv_mfma(
    const __hip_bfloat16* __restrict__ xb, const __hip_bfloat16* __restrict__ wbt,
    __hip_bfloat16* __restrict__ qb, __hip_bfloat16* __restrict__ kb,
    __hip_bfloat16* __restrict__ vb) {
  __shared__ __align__(16) short As[128 * 64];
  __shared__ __align__(16) short Bs[128 * 64];
  const int tid = threadIdx.x;
  const int t0 = blockIdx.x * 128;
  const int n0 = blockIdx.y * 128;
  const int lane = tid & 63, wave = tid >> 6;
  const int wm = wave >> 1, wn = wave & 1;

  const __hip_bfloat16* asrc[4];
  const __hip_bfloat16* bsrc[4];
#pragma unroll
  for (int s = 0; s < 4; ++s) {
    int c = s * 256 + tid;
    int row = c >> 3, kc = c & 7;
    asrc[s] = xb + (size_t)(t0 + row) * 512 + kc * 8;
    bsrc[s] = wbt + (size_t)(n0 + row) * 512 + kc * 8;
  }
  char* abase = (char*)As + wave * 1024;
  char* bbase = (char*)Bs + wave * 1024;

  f32x4 acc[4][4] = {};
  const int arow = wm * 64 + (lane & 15);
  const int brow = wn * 64 + (lane & 15);
  const int koff = (lane >> 4) * 8;

  for (int kt = 0; kt < 512; kt += 64) {
#pragma unroll
    for (int s = 0; s < 4; ++s) gload_lds16(asrc[s] + kt, abase + s * 4096);
#pragma unroll
    for (int s = 0; s < 4; ++s) gload_lds16(bsrc[s] + kt, bbase + s * 4096);
    __syncthreads();
    bf16x8 af[2][4], bfr[2][4];
#pragma unroll
    for (int kk = 0; kk < 2; ++kk) {
#pragma unroll
      for (int mf = 0; mf < 4; ++mf)
        af[kk][mf] = *(const bf16x8*)&As[(arow + mf * 16) * 64 + kk * 32 + koff];
#pragma unroll
      for (int nf = 0; nf < 4; ++nf)
        bfr[kk][nf] = *(const bf16x8*)&Bs[(brow + nf * 16) * 64 + kk * 32 + koff];
    }
#pragma unroll
    for (int kk = 0; kk < 2; ++kk)
#pragma unroll
      for (int mf = 0; mf < 4; ++mf)
#pragma unroll
        for (int nf = 0; nf < 4; ++nf)
          acc[mf][nf] = __builtin_amdgcn_mfma_f32_16x16x32_bf16(
              af[kk][mf], bfr[kk][nf], acc[mf][nf], 0, 0, 0);
    __syncthreads();
  }

  // epilogue: q/k -> [tok49][d32] windowed; v -> transposed [d32][tok56]
  int sp[4]; size_t nfoff[4];
#pragma unroll
  for (int nf = 0; nf < 4; ++nf) {
    int n = n0 + wn * 64 + nf * 16 + (lane & 15);
    sp[nf] = n >> 9;
    int hc = n & 511, hh = hc >> 5, d = hc & 31;
    nfoff[nf] = (sp[nf] == 2) ? ((size_t)hh * VT_HEAD + (size_t)d * 56)
                              : ((size_t)hh * HEAD_STRIDE + d);
  }
#pragma unroll
  for (int mf = 0; mf < 4; ++mf) {
#pragma unroll
    for (int r = 0; r < 4; ++r) {
      int t = t0 + wm * 64 + mf * 16 + (lane >> 4) * 4 + r;
      int b, i, j;
      token_decode(t, b, i, j);
      int win = (i / 7) * 8 + (j / 7);
      int pos = (i % 7) * 7 + (j % 7);
      size_t rqk = (size_t)b * BATCH_STRIDE + (size_t)win * WIN_ELEMS + pos * 32;
      size_t rv  = (size_t)b * VT_BATCH + (size_t)win * VT_WIN + pos;
#pragma unroll
      for (int nf = 0; nf < 4; ++nf) {
        __hip_bfloat16 val = __float2bfloat16(acc[mf][nf][r]);
        if (sp[nf] == 0)      qb[rqk + nfoff[nf]] = val;
        else if (sp[nf] == 1) kb[rqk + nfoff[nf]] = val;
        else                  vb[rv + nfoff[nf]] = val;
      }
    }
  }
}

// ---------------- K2: attention via MFMA, one wave per (b,h,win) ----------------
__global__ __launch_bounds__(256) void k_attn_mfma(
    const __hip_bfloat16* __restrict__ qb, const __hip_bfloat16* __restrict__ kb,
    const __hip_bfloat16* __restrict__ vt, const float* __restrict__ biasT,
    __hip_bfloat16* __restrict__ ab) {
  __shared__ __align__(16) __hip_bfloat16 P[4][64 * 72];   // per-wave P[query][key]
  const int tid = threadIdx.x, lane = tid & 63, wave = tid >> 6;
  const int gid = blockIdx.x * 4 + wave;                   // (b*16+h)*64 + win
  const int win = gid & 63, h = (gid >> 6) & 15;
  const int wtype = (((win >> 3) == 7) ? 1 : 0) | (((win & 7) == 7) ? 2 : 0);
  const size_t qkbase = (size_t)gid * WIN_ELEMS;
  const size_t vbase = (size_t)gid * VT_WIN;
  const int fr = lane & 15, fo = (lane >> 4) * 8;

  // Q,K fragments straight from global ([tok][d32], d==K of MFMA)
  bf16x8 kf[4], qf[4];
#pragma unroll
  for (int f = 0; f < 4; ++f) {
    kf[f] = *(const bf16x8*)(kb + qkbase + (size_t)(f * 16 + fr) * 32 + fo);
    qf[f] = *(const bf16x8*)(qb + qkbase + (size_t)(f * 16 + fr) * 32 + fo);
  }
  // S^T[key][query] = K @ Q^T
  f32x4 sacc[4][4] = {};   // [key-frag mf][query-frag nf]
#pragma unroll
  for (int mf = 0; mf < 4; ++mf)
#pragma unroll
    for (int nf = 0; nf < 4; ++nf)
      sacc[mf][nf] = __builtin_amdgcn_mfma_f32_16x16x32_bf16(
          kf[mf], qf[nf], sacc[mf][nf], 0, 0, 0);

  // scale + bias/mask table (fragment-layout, coalesced float4)
  const float* bp = biasT + (size_t)(wtype * 16 + h) * 4096;
#pragma unroll
  for (int mf = 0; mf < 4; ++mf)
#pragma unroll
    for (int r = 0; r < 4; ++r) {
      float4 bv = *(const float4*)(bp + ((mf * 4 + r) * 64 + lane) * 4);
      sacc[mf][0][r] = fmaf(sacc[mf][0][r], SCALE, bv.x);
      sacc[mf][1][r] = fmaf(sacc[mf][1][r], SCALE, bv.y);
      sacc[mf][2][r] = fmaf(sacc[mf][2][r], SCALE, bv.z);
      sacc[mf][3][r] = fmaf(sacc[mf][3][r], SCALE, bv.w);
    }

  // softmax over keys (rows of S^T): per query col, 16 local + 2 shuffles
  float inv[4];
#pragma unroll
  for (int nf = 0; nf < 4; ++nf) {
    float m = sacc[0][nf][0];
#pragma unroll
    for (int mf = 0; mf < 4; ++mf)
#pragma unroll
      for (int r = 0; r < 4; ++r) m = fmaxf(m, sacc[mf][nf][r]);
    m = fmaxf(m, __shfl_xor(m, 16));
    m = fmaxf(m, __shfl_xor(m, 32));
    float sum = 0.f;
#pragma unroll
    for (int mf = 0; mf < 4; ++mf)
#pragma unroll
      for (int r = 0; r < 4; ++r) {
        float e = __expf(sacc[mf][nf][r] - m);
        sacc[mf][nf][r] = e;
        sum += e;
      }
    sum += __shfl_xor(sum, 16);
    sum += __shfl_xor(sum, 32);
    inv[nf] = 1.0f / sum;
  }

  // write P[query][key] (bf16) to LDS, transposed back for PV A-operand
  __hip_bfloat16* pw = P[wave];
#pragma unroll
  for (int mf = 0; mf < 4; ++mf)
#pragma unroll
    for (int r = 0; r < 4; ++r) {
      int key = mf * 16 + (lane >> 4) * 4 + r;
#pragma unroll
      for (int nf = 0; nf < 4; ++nf) {
        int query = nf * 16 + fr;
        pw[query * 72 + key] = __float2bfloat16(sacc[mf][nf][r] * inv[nf]);
      }
    }

  // O = P @ V via MFMA; V^T layout gives contiguous B-frags
  f32x4 oacc[4][2] = {};
#pragma unroll
  for (int kk = 0; kk < 2; ++kk) {
    bf16x8 vf[2];
#pragma unroll
    for (int n2 = 0; n2 < 2; ++n2)
      vf[n2] = *(const bf16x8*)(vt + vbase + (size_t)(n2 * 16 + fr) * 56 + kk * 32 + fo);
#pragma unroll
    for (int mf = 0; mf < 4; ++mf) {
      bf16x8 pa = *(const bf16x8*)&pw[(mf * 16 + fr) * 72 + kk * 32 + fo];
#pragma unroll
      for (int n2 = 0; n2 < 2; ++n2)
        oacc[mf][n2] = __builtin_amdgcn_mfma_f32_16x16x32_bf16(
            pa, vf[n2], oacc[mf][n2], 0, 0, 0);
    }
  }

  // store O rows < 49 to windowed [tok49][d32]
#pragma unroll
  for (int mf = 0; mf < 4; ++mf)
#pragma unroll
    for (int r = 0; r < 4; ++r) {
      int row = mf * 16 + (lane >> 4) * 4 + r;
      if (row < 49) {
#pragma unroll
        for (int n2 = 0; n2 < 2; ++n2)
          ab[qkbase + (size_t)row * 32 + n2 * 16 + fr] =
              __float2bfloat16(oacc[mf][n2][r]);
      }
    }
}

// ---------------- K3: output GEMM, bf16 MFMA ----------------
__global__ __launch_bounds__(256) void k_out_mfma(
    const __hip_bfloat16* __restrict__ ab, const __hip_bfloat16* __restrict__ wot,
    const float* __restrict__ bias, float* __restrict__ out) {
  __shared__ __align__(16) short As[128 * 64];
  __shared__ __align__(16) short Bs[128 * 64];
  const int tid = threadIdx.x;
  const int t0 = blockIdx.x * 128;
  const int n0 = blockIdx.y * 128;
  const int lane = tid & 63, wave = tid >> 6;
  const int wm = wave >> 1, wn = wave & 1;

  size_t aoff[4];
  const __hip_bfloat16* bsrc[4];
#pragma unroll
  for (int s = 0; s < 4; ++s) {
    int c = s * 256 + tid;
    int row = c >> 3, kc = c & 7;
    int t = t0 + row, b, i, j;
    token_decode(t, b, i, j);
    int win = (i / 7) * 8 + (j / 7);
    int pos = (i % 7) * 7 + (j % 7);
    aoff[s] = (size_t)b * BATCH_STRIDE + (size_t)win * WIN_ELEMS + pos * 32 +
              (size_t)(kc >> 2) * HEAD_STRIDE + (kc & 3) * 8;
    bsrc[s] = wot + (size_t)(n0 + row) * 512 + kc * 8;
  }
  char* abase = (char*)As + wave * 1024;
  char* bbase = (char*)Bs + wave * 1024;

  f32x4 acc[4][4] = {};
  const int arow = wm * 64 + (lane & 15);
  const int brow = wn * 64 + (lane & 15);
  const int koff = (lane >> 4) * 8;

  for (int kt = 0; kt < 512; kt += 64) {
    size_t hoff = (size_t)(kt >> 5) * HEAD_STRIDE;
#pragma unroll
    for (int s = 0; s < 4; ++s) gload_lds16(ab + aoff[s] + hoff, abase + s * 4096);
#pragma unroll
    for (int s = 0; s < 4; ++s) gload_lds16(bsrc[s] + kt, bbase + s * 4096);
    __syncthreads();
    bf16x8 af[2][4], bfr[2][4];
#pragma unroll
    for (int kk = 0; kk < 2; ++kk) {
#pragma unroll
      for (int mf = 0; mf < 4; ++mf)
        af[kk][mf] = *(const bf16x8*)&As[(arow + mf * 16) * 64 + kk * 32 + koff];
#pragma unroll
      for (int nf = 0; nf < 4; ++nf)
        bfr[kk][nf] = *(const bf16x8*)&Bs[(brow + nf * 16) * 64 + kk * 32 + koff];
    }
#pragma unroll
    for (int kk = 0; kk < 2; ++kk)
#pragma unroll
      for (int mf = 0; mf < 4; ++mf)
#pragma unroll
        for (int nf = 0; nf < 4; ++nf)
          acc[mf][nf] = __builtin_amdgcn_mfma_f32_16x16x32_bf16(
              af[kk][mf], bfr[kk][nf], acc[mf][nf], 0, 0, 0);
    __syncthreads();
  }

  float bia[4];
#pragma unroll
  for (int nf = 0; nf < 4; ++nf)
    bia[nf] = bias[n0 + wn * 64 + nf * 16 + (lane & 15)];

#pragma unroll
  for (int mf = 0; mf < 4; ++mf) {
#pragma unroll
    for (int r = 0; r < 4; ++r) {
      int t = t0 + wm * 64 + mf * 16 + (lane >> 4) * 4 + r;
      int b, i, j;
      token_decode(t, b, i, j);
      int di = i + 3; if (di >= 56) di -= 56;
      int dj = j + 3; if (dj >= 56) dj -= 56;
      float* op = out + ((size_t)(b * 56 + di) * 56 + dj) * 512 + n0 + wn * 64 +
                  (lane & 15);
#pragma unroll
      for (int nf = 0; nf < 4; ++nf) op[nf * 16] = acc[mf][nf][r] + bia[nf];
    }
  }
}

extern "C" void kernel_launch(void* const* d_in, const int* in_sizes, int n_in,
                              void* d_out, int out_size, void* d_ws, size_t ws_size,
                              hipStream_t stream) {
  const float* x     = (const float*)d_in[0];
  const float* w_qkv = (const float*)d_in[1];
  const float* pe    = (const float*)d_in[2];
  const float* w_out = (const float*)d_in[3];
  const float* b_out = (const float*)d_in[4];
  float* out = (float*)d_out;

  __hip_bfloat16* qb  = (__hip_bfloat16*)d_ws;          // 51,380,224
  __hip_bfloat16* kb  = qb + (size_t)QKV_ELEMS;         // 51,380,224
  __hip_bfloat16* vt  = kb + (size_t)QKV_ELEMS;         // 58,720,256 (V transposed)
  __hip_bfloat16* xb  = vt + (size_t)VT_ELEMS;          // 51,380,224 (aliased ab)
  __hip_bfloat16* ab  = xb;
  __hip_bfloat16* wbt = xb + (size_t)QKV_ELEMS;         // 786,432
  __hip_bfloat16* wot = wbt + (size_t)(1536 * 512);     // 262,144
  float* biasT = (float*)(wot + (size_t)(512 * 512));   // 262,144 f32 (1 MB)

  k_zero_vpad<<<dim3(4096), dim3(256), 0, stream>>>(vt);
  k_prep_x<<<dim3(25088), dim3(256), 0, stream>>>(x, xb);
  k_transpose<<<dim3(24, 8), dim3(256), 0, stream>>>(w_qkv, wbt, 512, 1536);
  k_transpose<<<dim3(8, 8), dim3(256), 0, stream>>>(w_out, wot, 512, 512);
  k_prep_bias<<<dim3(1024), dim3(256), 0, stream>>>(pe, biasT);
  k_qkv_mfma<<<dim3(784, 12), dim3(256), 0, stream>>>(xb, wbt, qb, kb, vt);
  k_attn_mfma<<<dim3(8192), dim3(256), 0, stream>>>(qb, kb, vt, biasT, ab);
  k_out_mfma<<<dim3(784, 4), dim3(256), 0, stream>>>(ab, wot, b_out, out);
}

// Round 4
// 566.988 us; speedup vs baseline: 5.4945x; 1.2212x over previous
//
#include <hip/hip_runtime.h>
#include <hip/hip_bf16.h>
#include <stdint.h>

// Swin window attention, B=32, H=W=56, DIM=512, HEADS=16, HD=32, WS=7, shift=3.
// Round 4: XCD-chunked grid swizzle on both GEMMs (A-tile L2 reuse within an XCD);
// V stored coalesced like Q/K, transposed per-wave in LDS inside k_attn.

#define NWIN 64
#define NTOK 49
#define WIN_ELEMS 1568        // 49*32
#define HEAD_STRIDE 100352    // 64*49*32
#define BATCH_STRIDE 1605632  // 16*64*49*32
#define QKV_ELEMS 51380224    // 32*16*64*49*32
#define SCALE 0.17677669529663687f

typedef __attribute__((ext_vector_type(8))) short bf16x8;
typedef __attribute__((ext_vector_type(4))) float f32x4;

#define AS1 __attribute__((address_space(1)))
#define AS3 __attribute__((address_space(3)))

struct __align__(16) bf8 { __hip_bfloat16 h[8]; };

__device__ __forceinline__ void gload_lds16(const void* g, void* l) {
  __builtin_amdgcn_global_load_lds((const AS1 unsigned int*)g,
                                   (AS3 unsigned int*)l, 16, 0, 0);
}

__device__ __forceinline__ void token_decode(int t, int& b, int& i, int& j) {
  b = t / 3136;
  int r = t - b * 3136;
  i = r / 56;
  j = r - i * 56;
}

// ---------------- P1: x -> bf16, roll(-3,-3) fused, token-major ----------------
__global__ __launch_bounds__(256) void k_prep_x(const float* __restrict__ x,
                                                __hip_bfloat16* __restrict__ xb) {
  int idx = blockIdx.x * 256 + threadIdx.x;
  int t = idx >> 6;
  int c = (idx & 63) * 8;
  int b, i, j;
  token_decode(t, b, i, j);
  int si = i + 3; if (si >= 56) si -= 56;
  int sj = j + 3; if (sj >= 56) sj -= 56;
  const float* src = x + ((size_t)(b * 56 + si) * 56 + sj) * 512 + c;
  float4 a0 = *(const float4*)src;
  float4 a1 = *(const float4*)(src + 4);
  bf8 o;
  o.h[0] = __float2bfloat16(a0.x); o.h[1] = __float2bfloat16(a0.y);
  o.h[2] = __float2bfloat16(a0.z); o.h[3] = __float2bfloat16(a0.w);
  o.h[4] = __float2bfloat16(a1.x); o.h[5] = __float2bfloat16(a1.y);
  o.h[6] = __float2bfloat16(a1.z); o.h[7] = __float2bfloat16(a1.w);
  *(bf8*)(xb + (size_t)t * 512 + c) = o;
}

// ---------------- P2/P3: fp32 [K][N] -> bf16 [N][K] transpose ----------------
__global__ __launch_bounds__(256) void k_transpose(const float* __restrict__ in,
                                                   __hip_bfloat16* __restrict__ out,
                                                   int K, int N) {
  __shared__ float tl[64][65];
  const int nb = blockIdx.x * 64, kb = blockIdx.y * 64;
  const int tid = threadIdx.x;
#pragma unroll
  for (int s = 0; s < 16; ++s) {
    int idx = s * 256 + tid; int r = idx >> 6, c = idx & 63;
    tl[r][c] = in[(size_t)(kb + r) * N + nb + c];
  }
  __syncthreads();
#pragma unroll
  for (int s = 0; s < 16; ++s) {
    int idx = s * 256 + tid; int r = idx >> 6, c = idx & 63;
    out[(size_t)(nb + r) * K + kb + c] = __float2bfloat16(tl[c][r]);
  }
}

// ---------------- P4: bias table in MFMA fragment layout ----------------
__global__ __launch_bounds__(256) void k_prep_bias(const float* __restrict__ pe,
                                                   float* __restrict__ biasT) {
  int id = blockIdx.x * 256 + threadIdx.x;      // 262144 total
  int whid = id >> 12;
  int wtype = whid >> 4, h = whid & 15;
  int mid = id & 4095;
  int mf = mid >> 10, r = (mid >> 8) & 3, lane = (mid >> 2) & 63, nf = mid & 3;
  int key = mf * 16 + (lane >> 4) * 4 + r;
  int query = nf * 16 + (lane & 15);
  float v;
  if (key >= 49 || query >= 49) {
    v = -1e30f;
  } else {
    int i = query, j = key;
    int xi = i / 7, yi = i - xi * 7;
    int xj = j / 7, yj = j - xj * 7;
    int dx = xj - xi; if (dx < 0) dx += 13;
    int dy = yj - yi; if (dy < 0) dy += 13;
    v = pe[(dx * 13 + dy) * 16 + h];
    if ((wtype & 1) && ((xi >= 4) != (xj >= 4))) v = -1e30f;
    if ((wtype & 2) && ((yi >= 4) != (yj >= 4))) v = -1e30f;
  }
  biasT[id] = v;
}

// ---------------- K1: QKV GEMM, bf16 MFMA ----------------
// M=100352, N=1536, K=512. 128x128 tile, BK=64, 4 waves (2x2), 64x64 per wave.
// XCD-chunked block swizzle: lid&7 = XCD, contiguous work chunk per XCD, n fastest.
__global__ __launch_bounds__(256) void k_qkv_mfma(
    const __hip_bfloat16* __restrict__ xb, const __hip_bfloat16* __restrict__ wbt,
    __hip_bfloat16* __restrict__ qb, __hip_bfloat16* __restrict__ kb,
    __hip_bfloat16* __restrict__ vb) {
  __shared__ __align__(16) short As[128 * 64];
  __shared__ __align__(16) short Bs[128 * 64];
  const int tid = threadIdx.x;
  const int lid = blockIdx.x;                 // 9408 blocks
  const int wid = (lid & 7) * 1176 + (lid >> 3);
  const int t0 = (wid / 12) * 128;
  const int n0 = (wid % 12) * 128;
  const int lane = tid & 63, wave = tid >> 6;
  const int wm = wave >> 1, wn = wave & 1;

  const __hip_bfloat16* asrc[4];
  const __hip_bfloat16* bsrc[4];
#pragma unroll
  for (int s = 0; s < 4; ++s) {
    int c = s * 256 + tid;
    int row = c >> 3, kc = c & 7;
    asrc[s] = xb + (size_t)(t0 + row) * 512 + kc * 8;
    bsrc[s] = wbt + (size_t)(n0 + row) * 512 + kc * 8;
  }
  char* abase = (char*)As + wave * 1024;
  char* bbase = (char*)Bs + wave * 1024;

  f32x4 acc[4][4] = {};
  const int arow = wm * 64 + (lane & 15);
  const int brow = wn * 64 + (lane & 15);
  const int koff = (lane >> 4) * 8;

  for (int kt = 0; kt < 512; kt += 64) {
#pragma unroll
    for (int s = 0; s < 4; ++s) gload_lds16(asrc[s] + kt, abase + s * 4096);
#pragma unroll
    for (int s = 0; s < 4; ++s) gload_lds16(bsrc[s] + kt, bbase + s * 4096);
    __syncthreads();
    bf16x8 af[2][4], bfr[2][4];
#pragma unroll
    for (int kk = 0; kk < 2; ++kk) {
#pragma unroll
      for (int mf = 0; mf < 4; ++mf)
        af[kk][mf] = *(const bf16x8*)&As[(arow + mf * 16) * 64 + kk * 32 + koff];
#pragma unroll
      for (int nf = 0; nf < 4; ++nf)
        bfr[kk][nf] = *(const bf16x8*)&Bs[(brow + nf * 16) * 64 + kk * 32 + koff];
    }
#pragma unroll
    for (int kk = 0; kk < 2; ++kk)
#pragma unroll
      for (int mf = 0; mf < 4; ++mf)
#pragma unroll
        for (int nf = 0; nf < 4; ++nf)
          acc[mf][nf] = __builtin_amdgcn_mfma_f32_16x16x32_bf16(
              af[kk][mf], bfr[kk][nf], acc[mf][nf], 0, 0, 0);
    __syncthreads();
  }

  // epilogue: q/k/v all -> windowed [b][h][win][pos49][d32]
  __hip_bfloat16* obs[4];
#pragma unroll
  for (int nf = 0; nf < 4; ++nf) {
    int n = n0 + wn * 64 + nf * 16 + (lane & 15);
    int sp = n >> 9, hc = n & 511, h = hc >> 5, d = hc & 31;
    obs[nf] = (sp == 0 ? qb : (sp == 1 ? kb : vb)) + (size_t)h * HEAD_STRIDE + d;
  }
#pragma unroll
  for (int mf = 0; mf < 4; ++mf) {
#pragma unroll
    for (int r = 0; r < 4; ++r) {
      int t = t0 + wm * 64 + mf * 16 + (lane >> 4) * 4 + r;
      int b, i, j;
      token_decode(t, b, i, j);
      int win = (i / 7) * 8 + (j / 7);
      int pos = (i % 7) * 7 + (j % 7);
      size_t off = (size_t)b * BATCH_STRIDE + (size_t)win * WIN_ELEMS + pos * 32;
#pragma unroll
      for (int nf = 0; nf < 4; ++nf)
        obs[nf][off] = __float2bfloat16(acc[mf][nf][r]);
    }
  }
}

// ---------------- K2: attention via MFMA, one wave per (b,h,win) ----------------
__global__ __launch_bounds__(256) void k_attn_mfma(
    const __hip_bfloat16* __restrict__ qb, const __hip_bfloat16* __restrict__ kb,
    const __hip_bfloat16* __restrict__ vb, const float* __restrict__ biasT,
    __hip_bfloat16* __restrict__ ab) {
  __shared__ __align__(16) __hip_bfloat16 P[4][64 * 72];   // per-wave P[query][key]
  __shared__ __align__(16) __hip_bfloat16 VT[4][32 * 64];  // per-wave V^T[d][pos^swz]
  const int tid = threadIdx.x, lane = tid & 63, wave = tid >> 6;
  const int gid = blockIdx.x * 4 + wave;                   // (b*16+h)*64 + win
  const int win = gid & 63, h = (gid >> 6) & 15;
  const int wtype = (((win >> 3) == 7) ? 1 : 0) | (((win & 7) == 7) ? 2 : 0);
  const size_t qkbase = (size_t)gid * WIN_ELEMS;
  const int fr = lane & 15, fo = (lane >> 4) * 8;

  // issue V loads early (196 bf8 chunks over 64 lanes, 4 iters)
  bf8 v8[4];
#pragma unroll
  for (int it = 0; it < 4; ++it) {
    int c = it * 64 + lane;
    if (c < 196) v8[it] = *(const bf8*)(vb + qkbase + (size_t)c * 8);
  }

  // Q,K fragments straight from global ([tok][d32], d==K of MFMA)
  bf16x8 kf[4], qf[4];
#pragma unroll
  for (int f = 0; f < 4; ++f) {
    kf[f] = *(const bf16x8*)(kb + qkbase + (size_t)(f * 16 + fr) * 32 + fo);
    qf[f] = *(const bf16x8*)(qb + qkbase + (size_t)(f * 16 + fr) * 32 + fo);
  }

  // zero VT (pads pos 49..63 and unwritten rows), then transpose V into it
  __hip_bfloat16* vtw = VT[wave];
  {
    bf16x8 zz = {};
#pragma unroll
    for (int z = 0; z < 4; ++z) *(bf16x8*)&vtw[z * 512 + lane * 8] = zz;
  }
#pragma unroll
  for (int it = 0; it < 4; ++it) {
    int c = it * 64 + lane;
    if (c < 196) {
      int pos = c >> 2, d0 = (c & 3) * 8;
#pragma unroll
      for (int u = 0; u < 8; ++u) {
        int d = d0 + u;
        vtw[d * 64 + (pos ^ ((d & 7) << 3))] = v8[it].h[u];
      }
    }
  }

  // S^T[key][query] = K @ Q^T
  f32x4 sacc[4][4] = {};   // [key-frag mf][query-frag nf]
#pragma unroll
  for (int mf = 0; mf < 4; ++mf)
#pragma unroll
    for (int nf = 0; nf < 4; ++nf)
      sacc[mf][nf] = __builtin_amdgcn_mfma_f32_16x16x32_bf16(
          kf[mf], qf[nf], sacc[mf][nf], 0, 0, 0);

  // scale + bias/mask table (fragment-layout, coalesced float4)
  const float* bp = biasT + (size_t)(wtype * 16 + h) * 4096;
#pragma unroll
  for (int mf = 0; mf < 4; ++mf)
#pragma unroll
    for (int r = 0; r < 4; ++r) {
      float4 bv = *(const float4*)(bp + ((mf * 4 + r) * 64 + lane) * 4);
      sacc[mf][0][r] = fmaf(sacc[mf][0][r], SCALE, bv.x);
      sacc[mf][1][r] = fmaf(sacc[mf][1][r], SCALE, bv.y);
      sacc[mf][2][r] = fmaf(sacc[mf][2][r], SCALE, bv.z);
      sacc[mf][3][r] = fmaf(sacc[mf][3][r], SCALE, bv.w);
    }

  // softmax over keys (rows of S^T): per query col, 16 local + 2 shuffles
  float inv[4];
#pragma unroll
  for (int nf = 0; nf < 4; ++nf) {
    float m = sacc[0][nf][0];
#pragma unroll
    for (int mf = 0; mf < 4; ++mf)
#pragma unroll
      for (int r = 0; r < 4; ++r) m = fmaxf(m, sacc[mf][nf][r]);
    m = fmaxf(m, __shfl_xor(m, 16));
    m = fmaxf(m, __shfl_xor(m, 32));
    float sum = 0.f;
#pragma unroll
    for (int mf = 0; mf < 4; ++mf)
#pragma unroll
      for (int r = 0; r < 4; ++r) {
        float e = __expf(sacc[mf][nf][r] - m);
        sacc[mf][nf][r] = e;
        sum += e;
      }
    sum += __shfl_xor(sum, 16);
    sum += __shfl_xor(sum, 32);
    inv[nf] = 1.0f / sum;
  }

  // write P[query][key] (bf16) to LDS, transposed back for PV A-operand
  __hip_bfloat16* pw = P[wave];
#pragma unroll
  for (int mf = 0; mf < 4; ++mf)
#pragma unroll
    for (int r = 0; r < 4; ++r) {
      int key = mf * 16 + (lane >> 4) * 4 + r;
#pragma unroll
      for (int nf = 0; nf < 4; ++nf) {
        int query = nf * 16 + fr;
        pw[query * 72 + key] = __float2bfloat16(sacc[mf][nf][r] * inv[nf]);
      }
    }

  // O = P @ V via MFMA; V^T from per-wave LDS (XOR-swizzled pos)
  f32x4 oacc[4][2] = {};
#pragma unroll
  for (int kk = 0; kk < 2; ++kk) {
    bf16x8 vf[2];
#pragma unroll
    for (int n2 = 0; n2 < 2; ++n2) {
      int d = n2 * 16 + fr;
      vf[n2] = *(const bf16x8*)&vtw[d * 64 + ((kk * 32 + fo) ^ ((d & 7) << 3))];
    }
#pragma unroll
    for (int mf = 0; mf < 4; ++mf) {
      bf16x8 pa = *(const bf16x8*)&pw[(mf * 16 + fr) * 72 + kk * 32 + fo];
#pragma unroll
      for (int n2 = 0; n2 < 2; ++n2)
        oacc[mf][n2] = __builtin_amdgcn_mfma_f32_16x16x32_bf16(
            pa, vf[n2], oacc[mf][n2], 0, 0, 0);
    }
  }

  // store O rows < 49 to windowed [tok49][d32]
#pragma unroll
  for (int mf = 0; mf < 4; ++mf)
#pragma unroll
    for (int r = 0; r < 4; ++r) {
      int row = mf * 16 + (lane >> 4) * 4 + r;
      if (row < 49) {
#pragma unroll
        for (int n2 = 0; n2 < 2; ++n2)
          ab[qkbase + (size_t)row * 32 + n2 * 16 + fr] =
              __float2bfloat16(oacc[mf][n2][r]);
      }
    }
}

// ---------------- K3: output GEMM, bf16 MFMA ----------------
// M=100352, N=512, K=512. XCD-chunked swizzle, n fastest within chunk.
__global__ __launch_bounds__(256) void k_out_mfma(
    const __hip_bfloat16* __restrict__ ab, const __hip_bfloat16* __restrict__ wot,
    const float* __restrict__ bias, float* __restrict__ out) {
  __shared__ __align__(16) short As[128 * 64];
  __shared__ __align__(16) short Bs[128 * 64];
  const int tid = threadIdx.x;
  const int lid = blockIdx.x;                 // 3136 blocks
  const int wid = (lid & 7) * 392 + (lid >> 3);
  const int t0 = (wid >> 2) * 128;
  const int n0 = (wid & 3) * 128;
  const int lane = tid & 63, wave = tid >> 6;
  const int wm = wave >> 1, wn = wave & 1;

  size_t aoff[4];
  const __hip_bfloat16* bsrc[4];
#pragma unroll
  for (int s = 0; s < 4; ++s) {
    int c = s * 256 + tid;
    int row = c >> 3, kc = c & 7;
    int t = t0 + row, b, i, j;
    token_decode(t, b, i, j);
    int win = (i / 7) * 8 + (j / 7);
    int pos = (i % 7) * 7 + (j % 7);
    aoff[s] = (size_t)b * BATCH_STRIDE + (size_t)win * WIN_ELEMS + pos * 32 +
              (size_t)(kc >> 2) * HEAD_STRIDE + (kc & 3) * 8;
    bsrc[s] = wot + (size_t)(n0 + row) * 512 + kc * 8;
  }
  char* abase = (char*)As + wave * 1024;
  char* bbase = (char*)Bs + wave * 1024;

  f32x4 acc[4][4] = {};
  const int arow = wm * 64 + (lane & 15);
  const int brow = wn * 64 + (lane & 15);
  const int koff = (lane >> 4) * 8;

  for (int kt = 0; kt < 512; kt += 64) {
    size_t hoff = (size_t)(kt >> 5) * HEAD_STRIDE;
#pragma unroll
    for (int s = 0; s < 4; ++s) gload_lds16(ab + aoff[s] + hoff, abase + s * 4096);
#pragma unroll
    for (int s = 0; s < 4; ++s) gload_lds16(bsrc[s] + kt, bbase + s * 4096);
    __syncthreads();
    bf16x8 af[2][4], bfr[2][4];
#pragma unroll
    for (int kk = 0; kk < 2; ++kk) {
#pragma unroll
      for (int mf = 0; mf < 4; ++mf)
        af[kk][mf] = *(const bf16x8*)&As[(arow + mf * 16) * 64 + kk * 32 + koff];
#pragma unroll
      for (int nf = 0; nf < 4; ++nf)
        bfr[kk][nf] = *(const bf16x8*)&Bs[(brow + nf * 16) * 64 + kk * 32 + koff];
    }
#pragma unroll
    for (int kk = 0; kk < 2; ++kk)
#pragma unroll
      for (int mf = 0; mf < 4; ++mf)
#pragma unroll
        for (int nf = 0; nf < 4; ++nf)
          acc[mf][nf] = __builtin_amdgcn_mfma_f32_16x16x32_bf16(
              af[kk][mf], bfr[kk][nf], acc[mf][nf], 0, 0, 0);
    __syncthreads();
  }

  float bia[4];
#pragma unroll
  for (int nf = 0; nf < 4; ++nf)
    bia[nf] = bias[n0 + wn * 64 + nf * 16 + (lane & 15)];

#pragma unroll
  for (int mf = 0; mf < 4; ++mf) {
#pragma unroll
    for (int r = 0; r < 4; ++r) {
      int t = t0 + wm * 64 + mf * 16 + (lane >> 4) * 4 + r;
      int b, i, j;
      token_decode(t, b, i, j);
      int di = i + 3; if (di >= 56) di -= 56;
      int dj = j + 3; if (dj >= 56) dj -= 56;
      float* op = out + ((size_t)(b * 56 + di) * 56 + dj) * 512 + n0 + wn * 64 +
                  (lane & 15);
#pragma unroll
      for (int nf = 0; nf < 4; ++nf) op[nf * 16] = acc[mf][nf][r] + bia[nf];
    }
  }
}

extern "C" void kernel_launch(void* const* d_in, const int* in_sizes, int n_in,
                              void* d_out, int out_size, void* d_ws, size_t ws_size,
                              hipStream_t stream) {
  const float* x     = (const float*)d_in[0];
  const float* w_qkv = (const float*)d_in[1];
  const float* pe    = (const float*)d_in[2];
  const float* w_out = (const float*)d_in[3];
  const float* b_out = (const float*)d_in[4];
  float* out = (float*)d_out;

  __hip_bfloat16* qb  = (__hip_bfloat16*)d_ws;          // 51,380,224
  __hip_bfloat16* kb  = qb + (size_t)QKV_ELEMS;         // 51,380,224
  __hip_bfloat16* vb  = kb + (size_t)QKV_ELEMS;         // 51,380,224
  __hip_bfloat16* xb  = vb + (size_t)QKV_ELEMS;         // 51,380,224 (aliased ab)
  __hip_bfloat16* ab  = xb;
  __hip_bfloat16* wbt = xb + (size_t)QKV_ELEMS;         // 786,432
  __hip_bfloat16* wot = wbt + (size_t)(1536 * 512);     // 262,144
  float* biasT = (float*)(wot + (size_t)(512 * 512));   // 262,144 f32 (1 MB)

  k_prep_x<<<dim3(25088), dim3(256), 0, stream>>>(x, xb);
  k_transpose<<<dim3(24, 8), dim3(256), 0, stream>>>(w_qkv, wbt, 512, 1536);
  k_transpose<<<dim3(8, 8), dim3(256), 0, stream>>>(w_out, wot, 512, 512);
  k_prep_bias<<<dim3(1024), dim3(256), 0, stream>>>(pe, biasT);
  k_qkv_mfma<<<dim3(9408), dim3(256), 0, stream>>>(xb, wbt, qb, kb, vb);
  k_attn_mfma<<<dim3(8192), dim3(256), 0, stream>>>(qb, kb, vb, biasT, ab);
  k_out_mfma<<<dim3(3136), dim3(256), 0, stream>>>(ab, wot, b_out, out);
}